// Round 1
// baseline (488.435 us; speedup 1.0000x reference)
//
#include <hip/hip_runtime.h>
#include <hip/hip_bf16.h>

#define N_TOK 4096
#define DIM   1024
#define VOCAB 32000
#define BM 256
#define BN 256
#define BK 64
#define SMOOTH 0.1f

typedef __attribute__((ext_vector_type(8))) short short8v;
typedef __attribute__((ext_vector_type(4))) float float4v;

__device__ __forceinline__ unsigned short f2bf(float f) {
  union { float f; unsigned u; } c; c.f = f;
  unsigned r = c.u + 0x7fffu + ((c.u >> 16) & 1u);
  return (unsigned short)(r >> 16);
}

// f32 -> bf16 (RNE) for BOTH tensors in one dispatch (trim launch gap).
__global__ void cvt_bf16_2(const float* __restrict__ a, unsigned short* __restrict__ da, int n4a,
                           const float* __restrict__ b, unsigned short* __restrict__ db, int n4b) {
  int i = blockIdx.x * blockDim.x + threadIdx.x;
  const float4* s; unsigned long long* d; int j;
  if (i < n4a)            { s = (const float4*)a; d = (unsigned long long*)da; j = i; }
  else if (i < n4a + n4b) { s = (const float4*)b; d = (unsigned long long*)db; j = i - n4a; }
  else return;
  float4 v = s[j];
  d[j] = (unsigned long long)f2bf(v.x)
       | ((unsigned long long)f2bf(v.y) << 16)
       | ((unsigned long long)f2bf(v.z) << 32)
       | ((unsigned long long)f2bf(v.w) << 48);
}

__device__ __forceinline__ void gload_lds16(const unsigned short* g, unsigned short* l) {
  __builtin_amdgcn_global_load_lds((const __attribute__((address_space(1))) unsigned int*)g,
                                   (__attribute__((address_space(3))) unsigned int*)l,
                                   16, 0, 0);
}

// logit[n, y_n] in exact f32: one wave per token row.
__global__ __launch_bounds__(256)
void tgt_dot(const float* __restrict__ x, const float* __restrict__ W,
             const int* __restrict__ y, float* __restrict__ tgtRow) {
  const int n = blockIdx.x * 4 + (threadIdx.x >> 6);
  const int lane = threadIdx.x & 63;
  const float4* xr = (const float4*)(x + (size_t)n * DIM);
  const float4* wr = (const float4*)(W + (size_t)y[n] * DIM);
  float d = 0.f;
#pragma unroll
  for (int i = 0; i < 4; ++i) {
    float4 a = xr[lane + 64 * i], b = wr[lane + 64 * i];
    d += a.x * b.x + a.y * b.y + a.z * b.z + a.w * b.w;
  }
#pragma unroll
  for (int off = 32; off > 0; off >>= 1) d += __shfl_xor(d, off, 64);
  if (lane == 0) tgtRow[n] = d;
}

// ---------------------------------------------------------------------------
// C = Xb[4096,1024] * Wb[32000,1024]^T, fused per-row sum(exp)/sum(logit).
// 256x256 tile, 8 waves (2x4, each owns 128x64), BK=64, 8-phase schedule:
// counted vmcnt(6) twice per 8 phases (never 0 in steady state), 1 half-tile
// (2 x global_load_lds) staged per phase, s_setprio(1) around each 16-MFMA
// cluster. LDS 128 KiB: As[2]/Bs[2] double buffer, 16B-colblock XOR swizzle
// (pos = cb ^ (row&7)) applied via pre-swizzled global source (linear
// global_load_lds dest) + swizzled ds_read — identical to the proven
// 0-bank-conflict pattern of the previous kernel.
//
// Slot discipline (quadrant order i0j0, i0j1, i1j1, i1j0; B-h0 held in regs):
//   buf0 slot last read:  A0@ph1  B0@ph1  B1@ph2  A1@ph3
//   buf1 slot last read:  A0@ph5  B0@ph5  B1@ph6  A1@ph7
//   stages (always >=1 barrier after last read of the slot):
//   ph1:A1(t+1)  ph2:A0(t+2) ph3:B0(t+2) ph4:B1(t+2) ph5:A1(t+2)
//   ph6:A0(t+3)  ph7:B0(t+3) ph8:B1(t+3)
//   vmcnt(6)@ph4: leaves t+2's {A0,B0,B1} in flight, t+1 fully landed.
//   vmcnt(6)@ph8: leaves t+3's {A0,B0,B1} in flight, t+2 fully landed.
// ---------------------------------------------------------------------------
__global__ __launch_bounds__(512, 2)
void gemm_ce(const unsigned short* __restrict__ Xb, const unsigned short* __restrict__ Wb,
             float* __restrict__ rowExp, float* __restrict__ rowSum) {
  __shared__ __align__(16) unsigned short As[2][BM * BK];  // 2 x 32 KB
  __shared__ __align__(16) unsigned short Bs[2][BN * BK];  // 2 x 32 KB

  // XCD-aware bijective swizzle (2000 % 8 == 0), token(ib)-fastest inside.
  const int bid = blockIdx.x;
  const int swz = (bid & 7) * 250 + (bid >> 3);
  const int ib = swz & 15;    // token tile 0..15
  const int jb = swz >> 4;    // vocab tile 0..124

  const int tid  = threadIdx.x;
  const int wid  = tid >> 6;
  const int lane = tid & 63;
  const int wr = wid >> 2;          // 0..1  (row half of C)
  const int wc = wid & 3;           // 0..3  (col quarter of C)
  const int quad = lane >> 4;
  const int r16  = lane & 15;
  const int r8   = r16 & 7;
  const int lrow = lane >> 3;       // staging: row within 8-row slab
  const int gcb  = (lane & 7) ^ (lrow & 7);  // pre-swizzled source colblock

  const int row0 = ib * BM;
  const int col0 = jb * BN;

  // per-lane staging base pointers (uniform per-call offsets fold to SGPR)
  const unsigned short* pA = Xb + (size_t)(row0 + wid * 8 + lrow) * DIM + gcb * 8;
  const unsigned short* pB = Wb + (size_t)(col0 + wid * 8 + lrow) * DIM + gcb * 8;

#define STAGE_A(b, h, kt) do { \
    gload_lds16(pA + (size_t)((h)*128      ) * DIM + (size_t)(kt) * 64, &As[b][(((h)*128      ) + wid*8) * BK]); \
    gload_lds16(pA + (size_t)((h)*128 + 64 ) * DIM + (size_t)(kt) * 64, &As[b][(((h)*128 + 64 ) + wid*8) * BK]); \
  } while (0)
#define STAGE_B(b, h, kt) do { \
    gload_lds16(pB + (size_t)((h)*128      ) * DIM + (size_t)(kt) * 64, &Bs[b][(((h)*128      ) + wid*8) * BK]); \
    gload_lds16(pB + (size_t)((h)*128 + 64 ) * DIM + (size_t)(kt) * 64, &Bs[b][(((h)*128 + 64 ) + wid*8) * BK]); \
  } while (0)

#define LOAD_A(b, ih) do { \
    _Pragma("unroll") for (int i = 0; i < 4; ++i) { \
      const int arow = (wr*128 + (ih)*64 + i*16 + r16) * BK; \
      af[i][0] = *(const short8v*)&As[b][arow + ((quad ^ r8) * 8)]; \
      af[i][1] = *(const short8v*)&As[b][arow + (((4 + quad) ^ r8) * 8)]; \
    } } while (0)
#define LOAD_B2(b, jh, dst) do { \
    _Pragma("unroll") for (int j = 0; j < 2; ++j) { \
      const int brow = (wc*64 + (jh)*32 + j*16 + r16) * BK; \
      dst[j][0] = *(const short8v*)&Bs[b][brow + ((quad ^ r8) * 8)]; \
      dst[j][1] = *(const short8v*)&Bs[b][brow + (((4 + quad) ^ r8) * 8)]; \
    } } while (0)

#define MFMA_Q(ih, jh, B) do { \
    __builtin_amdgcn_s_setprio(1); \
    _Pragma("unroll") for (int i = 0; i < 4; ++i) \
      _Pragma("unroll") for (int j = 0; j < 2; ++j) { \
        acc[(ih)*4+i][(jh)*2+j] = __builtin_amdgcn_mfma_f32_16x16x32_bf16(af[i][0], B[j][0], acc[(ih)*4+i][(jh)*2+j], 0, 0, 0); \
        acc[(ih)*4+i][(jh)*2+j] = __builtin_amdgcn_mfma_f32_16x16x32_bf16(af[i][1], B[j][1], acc[(ih)*4+i][(jh)*2+j], 0, 0, 0); \
      } \
    __builtin_amdgcn_s_setprio(0); } while (0)

#define BAR()   __builtin_amdgcn_s_barrier()
#define LGKM0() asm volatile("s_waitcnt lgkmcnt(0)" ::: "memory")
#define VM6()   asm volatile("s_waitcnt vmcnt(6)" ::: "memory")
#define VM0()   asm volatile("s_waitcnt vmcnt(0)" ::: "memory")

  float4v acc[8][4];
#pragma unroll
  for (int i = 0; i < 8; ++i)
#pragma unroll
    for (int j = 0; j < 4; ++j) acc[i][j] = (float4v){0.f, 0.f, 0.f, 0.f};

  short8v af[4][2], bf[2][2], bf0[2][2];

  // Prologue: tile0 full -> buf0; tile1 {A0,B0,B1} -> buf1 (A1 staged @ it0 ph1).
  STAGE_A(0, 0, 0); STAGE_B(0, 0, 0); STAGE_B(0, 1, 0); STAGE_A(0, 1, 0);
  STAGE_A(1, 0, 1); STAGE_B(1, 0, 1); STAGE_B(1, 1, 1);
  VM6();            // tile0's 8 loads landed; tile1's 6 still in flight
  BAR();

#pragma unroll 1
  for (int it = 0; it < 8; ++it) {
    const int t = 2 * it;
    const bool last = (it == 7);

    // ph1: quadrant (i0,j0) of tile t (buf0)
    LOAD_A(0, 0);
    LOAD_B2(0, 0, bf0);                    // held through ph4
    STAGE_A(1, 1, t + 1);                  // buf1.A1 freed @ prev ph7
    BAR(); LGKM0();
    MFMA_Q(0, 0, bf0);
    BAR();

    // ph2: (i0,j1)
    LOAD_B2(0, 1, bf);
    if (!last) STAGE_A(0, 0, t + 2);
    BAR(); LGKM0();
    MFMA_Q(0, 1, bf);
    BAR();

    // ph3: (i1,j1)
    LOAD_A(0, 1);
    if (!last) STAGE_B(0, 0, t + 2);
    BAR(); LGKM0();
    MFMA_Q(1, 1, bf);
    BAR();

    // ph4: (i1,j0) — no ds_reads (af=A1, bf0=B0 both held)
    if (!last) { STAGE_B(0, 1, t + 2); VM6(); }  // tile t+1 fully landed
    else       { VM0(); }                        // drain: tile 15 landed
    BAR(); LGKM0();
    MFMA_Q(1, 0, bf0);
    BAR();

    // ph5: (i0,j0) of tile t+1 (buf1)
    LOAD_A(1, 0);
    LOAD_B2(1, 0, bf0);
    if (!last) STAGE_A(0, 1, t + 2);
    BAR(); LGKM0();
    MFMA_Q(0, 0, bf0);
    BAR();

    // ph6: (i0,j1)
    LOAD_B2(1, 1, bf);
    if (!last) STAGE_A(1, 0, t + 3);
    BAR(); LGKM0();
    MFMA_Q(0, 1, bf);
    BAR();

    // ph7: (i1,j1)
    LOAD_A(1, 1);
    if (!last) STAGE_B(1, 0, t + 3);
    BAR(); LGKM0();
    MFMA_Q(1, 1, bf);
    BAR();

    // ph8: (i1,j0)
    if (!last) { STAGE_B(1, 1, t + 3); VM6(); }  // tile t+2 fully landed
    BAR(); LGKM0();
    MFMA_Q(1, 0, bf0);
    BAR();
  }

  // -------- Fused epilogue: per-row sum(exp(logit)), sum(logit). ----------
  // C/D layout per 16x16 frag: col = r16, row = quad*4 + reg.
  // Block-level LDS reduction first (4 wc-waves share each row) -> 2x fewer
  // global atomics. Reuse As (dead) as red[512]: [0..255]=exp, [256..511]=raw.
  __syncthreads();
  float* red = (float*)&As[0][0];
  red[tid] = 0.f;
  __syncthreads();
#pragma unroll
  for (int i = 0; i < 8; ++i)
#pragma unroll
    for (int r = 0; r < 4; ++r) {
      float se = 0.f, ss = 0.f;
#pragma unroll
      for (int j = 0; j < 4; ++j) {
        const float v = acc[i][j][r];
        ss += v;
        se += __expf(v);
      }
#pragma unroll
      for (int off = 1; off < 16; off <<= 1) {
        se += __shfl_xor(se, off, 64);
        ss += __shfl_xor(ss, off, 64);
      }
      if (r16 == 0) {
        const int rloc = wr * 128 + i * 16 + quad * 4 + r;
        atomicAdd(&red[rloc], se);
        atomicAdd(&red[256 + rloc], ss);
      }
    }
  __syncthreads();
  if (tid < 256) {
    atomicAdd(&rowExp[row0 + tid], red[tid]);
    atomicAdd(&rowSum[row0 + tid], red[256 + tid]);
  }
}

// loss = (1/N) sum lse - (1-s)/N * sum tgt - s/(N*V) * sum(all logits)
__global__ void finalize_kernel(const float* __restrict__ rowExp, const float* __restrict__ rowSum,
                                const float* __restrict__ tgtRow, float* __restrict__ out) {
  __shared__ float s1[256], s2[256], s3[256];
  const int t = threadIdx.x;
  float a = 0.f, b = 0.f, c = 0.f;
  for (int n = t; n < N_TOK; n += 256) {
    a += logf(rowExp[n]);
    b += rowSum[n];
    c += tgtRow[n];
  }
  s1[t] = a; s2[t] = b; s3[t] = c;
  __syncthreads();
  for (int o = 128; o > 0; o >>= 1) {
    if (t < o) { s1[t] += s1[t + o]; s2[t] += s2[t + o]; s3[t] += s3[t + o]; }
    __syncthreads();
  }
  if (t == 0) {
    const float inviN = 1.0f / (float)N_TOK;
    out[0] = s1[0] * inviN
           - (1.0f - SMOOTH) * s3[0] * inviN
           - SMOOTH * s2[0] / ((float)N_TOK * (float)VOCAB);
  }
}

extern "C" void kernel_launch(void* const* d_in, const int* in_sizes, int n_in,
                              void* d_out, int out_size, void* d_ws, size_t ws_size,
                              hipStream_t stream) {
  const float* x = (const float*)d_in[0];
  const float* W = (const float*)d_in[1];
  const int*   y = (const int*)d_in[2];
  float* out = (float*)d_out;

  char* ws = (char*)d_ws;
  float* rowExp = (float*)(ws);              // 4096 f32
  float* rowSum = (float*)(ws + 16384);      // 4096 f32
  float* tgtRow = (float*)(ws + 32768);      // 4096 f32 (fully written, no memset)
  unsigned short* Xb = (unsigned short*)(ws + 65536);                            // 8.4 MB
  unsigned short* Wb = (unsigned short*)(ws + 65536 + (size_t)N_TOK * DIM * 2);  // 65.5 MB

  hipMemsetAsync(ws, 0, 32768, stream);  // zero rowExp/rowSum (ws poisoned 0xAA)

  tgt_dot<<<N_TOK / 4, 256, 0, stream>>>(x, W, y, tgtRow);

  const int n4x = N_TOK * DIM / 4, n4w = VOCAB * DIM / 4;
  cvt_bf16_2<<<(n4x + n4w + 255) / 256, 256, 0, stream>>>(x, Xb, n4x, W, Wb, n4w);

  gemm_ce<<<(N_TOK / BM) * (VOCAB / BN), 512, 0, stream>>>(Xb, Wb, rowExp, rowSum);

  finalize_kernel<<<1, 256, 0, stream>>>(rowExp, rowSum, tgtRow, out);
}